// Round 10
// baseline (190.040 us; speedup 1.0000x reference)
//
#include <hip/hip_runtime.h>
#include <hip/hip_bf16.h>

#define NN 50000
#define NE 800000
#define HD 64
#define OD 16
#define CAP 64        // padded-CSR slots per node (mean deg = 16; P(>64) ~ 1e-18)
#define TILES 3125    // NN/16
#define AST 72        // LDS A/C row stride in u16 (144 B); 36 u32
#define SCATB 2048    // scatter blocks in k_pre
#define PSZ 6250      // NN / 8 partitions

typedef unsigned short u16;
typedef unsigned int u32;
typedef __attribute__((ext_vector_type(8))) short short8;
typedef __attribute__((ext_vector_type(4))) float f32x4;

__device__ __forceinline__ float bf2f(u16 v) { return __uint_as_float(((u32)v) << 16); }
__device__ __forceinline__ u16 f2bf(float f) {
  __hip_bfloat16 h = __float2bfloat16(f);
  return *reinterpret_cast<u16*>(&h);
}
__device__ __forceinline__ float ldf(const void* p, long i, bool f32m) {
  return f32m ? ((const float*)p)[i] : bf2f(((const u16*)p)[i]);
}
__device__ __forceinline__ int edge_at(const void* eidx, long pos, bool i64) {
  return i64 ? (int)((const long long*)eidx)[pos] : ((const int*)eidx)[pos];
}

// deterministic local dtype detects (same fixed words in every block -> consistent)
__device__ __forceinline__ bool detect_i64(const u32* e32, int lane) {
  return __ballot(e32[2 * lane + 1] != 0u) == 0ull;
}
__device__ __forceinline__ bool detect_f32(const u32* x32, int lane) {
  u32 v = x32[lane] & 0xffffu;
  int e = (int)((v >> 7) & 0xff);
  bool wild = (v != 0u) && (e < 100 || e > 140);
  return __popcll(__ballot(wild)) > 16;
}

// ONE pre-kernel: blocks [0,SCATB) = XCD-partitioned padded-CSR scatter;
// blocks [SCATB, SCATB+3125) = x->bf16 (f32 mode) + MFMA B/proj frags + biases.
__global__ __launch_bounds__(256) void k_pre(
    const void* __restrict__ x, const void* __restrict__ eidx,
    const void* __restrict__ Wl, const void* __restrict__ bl,
    const void* __restrict__ Wr, const void* __restrict__ Wo,
    const void* __restrict__ bo,
    int* __restrict__ deg, u16* __restrict__ csr, u32* __restrict__ spill,
    u16* __restrict__ xA, u16* __restrict__ wfrag, u16* __restrict__ pfrag,
    float* __restrict__ blf, float* __restrict__ bof,
    int* __restrict__ flags) {
  int lane = threadIdx.x & 63;
  if (blockIdx.x < SCATB) {
    bool i64 = detect_i64((const u32*)eidx, lane);
    int g = blockIdx.x & 7;
    int lo = g * PSZ, hi = lo + PSZ;
    int base = (blockIdx.x >> 3) * 256 + threadIdx.x;
    for (int e = base; e < NE; e += 65536) {
      int dst = edge_at(eidx, (long)NE + e, i64);
      if (dst >= lo && dst < hi) {
        int src = edge_at(eidx, e, i64);
        int pos = atomicAdd(&deg[dst], 1);
        if (pos < CAP) csr[(long)dst * CAP + pos] = (u16)src;
        else {
          int sp = atomicAdd(&flags[4], 1);
          spill[sp] = (u32)dst * 50000u + (u32)src;
        }
      }
    }
  } else {
    bool f32m = detect_f32((const u32*)x, lane);
    int i = (blockIdx.x - SCATB) * 256 + threadIdx.x;  // 0..799999
    if (f32m) {
      float4 v = ((const float4*)x)[i];
      u32 lo = (u32)f2bf(v.x) | ((u32)f2bf(v.y) << 16);
      u32 hi = (u32)f2bf(v.z) | ((u32)f2bf(v.w) << 16);
      ((u32*)xA)[2 * i] = lo;
      ((u32*)xA)[2 * i + 1] = hi;
    }
    if (i < 3 * 16 * 64 * 8) {  // B frags: k=32s+(lane>>4)*8+j, n=16c+(lane&15)
      int j = i & 7, ln = (i >> 3) & 63, f = (i >> 9) & 15, l = i >> 13;
      int s = f >> 2, c = f & 3;
      int k = 32 * s + ((ln >> 4) << 3) + j;
      int n = (c << 4) + (ln & 15);
      long wbase = (long)l * HD * HD;
      float v = (k < HD) ? ldf(Wl, wbase + (long)k * HD + n, f32m)
                         : ldf(Wr, wbase + (long)(k - HD) * HD + n, f32m);
      wfrag[i] = f2bf(v);
    }
    if (i < 2 * 64 * 8) {  // proj frags
      int j = i & 7, ln = (i >> 3) & 63, s = i >> 9;
      int k = 32 * s + ((ln >> 4) << 3) + j;
      pfrag[i] = f2bf(ldf(Wo, (long)k * OD + (ln & 15), f32m));
    }
    if (i < 3 * HD) blf[i] = ldf(bl, i, f32m);
    if (i < OD) bof[i] = ldf(bo, i, f32m);
  }
}

// fused SAGE layer: block = 4 waves = ONE 16-node tile.
// Gather is PHASE-SPLIT over the feature dim: phase ph reads only the
// 64 B half-line [ph*32, ph*32+32) of each neighbor row, so the phase
// working set is 50000*64 B = 3.2 MB -> resident in a 4 MiB XCD L2.
// Per load: 4 neighbors' half-rows (lane group grp=lane>>4, f=lane&15,
// 2 features/lane); neighbor idx via __shfl; reduce via shfl_xor(16/32).
// 2-node interleave keeps 8 loads in flight. Then 16-col MFMA slice/wave;
// doProj = fused 64->16 projection epilogue (wave 0).
__global__ __launch_bounds__(256, 8) void k_fused(
    const u16* __restrict__ xin_bf, const u16* __restrict__ xin_f32m,
    const u32* __restrict__ xorig32, u16* __restrict__ xout,
    const int* __restrict__ deg, const u16* __restrict__ csr,
    const u32* __restrict__ spill,
    const u16* __restrict__ wfrag, const u16* __restrict__ pfrag,
    const float* __restrict__ bl3, const float* __restrict__ bof,
    void* __restrict__ outp, int layer, int doProj,
    const int* __restrict__ flags) {
  __shared__ __align__(16) u16 aw[16 * AST];
  __shared__ float sbl[HD];
  __shared__ float sbo[OD];
  if (threadIdx.x < HD) sbl[threadIdx.x] = bl3[layer * HD + threadIdx.x];
  if (threadIdx.x < OD) sbo[threadIdx.x] = bof[threadIdx.x];
  int lane = threadIdx.x & 63;
  bool f32m = detect_f32(xorig32, lane);
  int spillcnt = __builtin_amdgcn_readfirstlane(flags[4]);
  const u16* xin = f32m ? xin_f32m : xin_bf;
  const u32* x32 = (const u32*)xin;

  int w = threadIdx.x >> 6;
  int nb = blockIdx.x * 16;
  int n0 = nb + 4 * w;
  int grp = lane >> 4;      // neighbor slot within a load
  int f = lane & 15;        // feature-pair index within the half
  u32* aw32 = (u32*)aw;

  // ---- prefetch degrees (16B broadcast) and all 4 csr index rows ----
  int4 dv = *(const int4*)(deg + n0);
  int dt[4] = {__builtin_amdgcn_readfirstlane(dv.x),
               __builtin_amdgcn_readfirstlane(dv.y),
               __builtin_amdgcn_readfirstlane(dv.z),
               __builtin_amdgcn_readfirstlane(dv.w)};
  int idx[4];
#pragma unroll
  for (int g = 0; g < 4; ++g) {
    int d = dt[g] < CAP ? dt[g] : CAP;
    idx[g] = (lane < d) ? (int)csr[(long)(n0 + g) * CAP + lane] : 0;
  }

  // ---- phase-split gather-mean ----
#pragma unroll
  for (int ph = 0; ph < 2; ++ph) {
    const u32* xph = x32 + ph * 16;  // half-row base (16 u32 = 64 B)
#pragma unroll
    for (int gp = 0; gp < 4; gp += 2) {
      int dA = dt[gp] < CAP ? dt[gp] : CAP;
      int dB = dt[gp + 1] < CAP ? dt[gp + 1] : CAP;
      int dmax = dA > dB ? dA : dB;
      float alo = 0.f, ahi = 0.f, blo = 0.f, bhi = 0.f;
      for (int j = 0; j < dmax; j += 16) {
        u32 va[4], vb[4];
#pragma unroll
        for (int p = 0; p < 4; ++p) {
          int sa = __shfl(idx[gp], j + 4 * p + grp);
          int sb = __shfl(idx[gp + 1], j + 4 * p + grp);
          va[p] = xph[(long)sa * 32 + f];
          vb[p] = xph[(long)sb * 32 + f];
        }
#pragma unroll
        for (int p = 0; p < 4; ++p) {
          int m = j + 4 * p + grp;
          u32 a = (m < dA) ? va[p] : 0u;
          u32 b = (m < dB) ? vb[p] : 0u;
          alo += __uint_as_float(a << 16);
          ahi += __uint_as_float(a & 0xffff0000u);
          blo += __uint_as_float(b << 16);
          bhi += __uint_as_float(b & 0xffff0000u);
        }
      }
      // reduce across the 4 lane-groups -> lanes 0-15 hold full sums
      alo += __shfl_xor(alo, 16); ahi += __shfl_xor(ahi, 16);
      blo += __shfl_xor(blo, 16); bhi += __shfl_xor(bhi, 16);
      alo += __shfl_xor(alo, 32); ahi += __shfl_xor(ahi, 32);
      blo += __shfl_xor(blo, 32); bhi += __shfl_xor(bhi, 32);
      if (spillcnt > 0) {  // cold path: only if some node exceeded CAP
#pragma unroll
        for (int q = 0; q < 2; ++q) {
          int n = n0 + gp + q;
          for (int base = 0; base < spillcnt; base += 64) {
            u32 p = (base + lane < spillcnt) ? spill[base + lane] : 0xffffffffu;
            u32 dd = p / 50000u;
            u32 ss = p - dd * 50000u;
            unsigned long long mk = __ballot(dd == (u32)n);
            while (mk) {
              int jj = __builtin_ctzll(mk);
              mk &= mk - 1;
              int s = __builtin_amdgcn_readlane((int)ss, jj);
              u32 v = xph[(long)s * 32 + f];
              float vlo = __uint_as_float(v << 16);
              float vhi = __uint_as_float(v & 0xffff0000u);
              if (q) { blo += vlo; bhi += vhi; }
              else   { alo += vlo; ahi += vhi; }
            }
          }
        }
      }
      if (lane < 16) {
        float rdA = 1.0f / (float)(dt[gp] > 0 ? dt[gp] : 1);
        float rdB = 1.0f / (float)(dt[gp + 1] > 0 ? dt[gp + 1] : 1);
        aw32[(4 * w + gp) * (AST / 2) + ph * 16 + f] =
            (u32)f2bf(alo * rdA) | ((u32)f2bf(ahi * rdA) << 16);
        aw32[(4 * w + gp + 1) * (AST / 2) + ph * 16 + f] =
            (u32)f2bf(blo * rdB) | ((u32)f2bf(bhi * rdB) << 16);
      }
    }
  }
  __syncthreads();

  // ---- A fragments (shared tile), B fragments straight from global ----
  int quad = lane >> 4, m16 = lane & 15;
  short8 a0 = *(const short8*)(aw + m16 * AST + quad * 8);        // k 0..31
  short8 a1 = *(const short8*)(aw + m16 * AST + 32 + quad * 8);   // k 32..63
  const u16* xrow = xin + (long)(nb + m16) * HD;
  short8 x2 = *(const short8*)(xrow + quad * 8);                  // k 64..95
  short8 x3 = *(const short8*)(xrow + 32 + quad * 8);             // k 96..127
  int c = w;  // this wave's col-tile
  const short8* bp = (const short8*)(wfrag + (long)layer * 16 * 64 * 8);
  short8 b0 = bp[(0 * 4 + c) * 64 + lane];
  short8 b1 = bp[(1 * 4 + c) * 64 + lane];
  short8 b2 = bp[(2 * 4 + c) * 64 + lane];
  short8 b3 = bp[(3 * 4 + c) * 64 + lane];
  float bb = sbl[c * 16 + m16];
  f32x4 acc = (f32x4){bb, bb, bb, bb};
  acc = __builtin_amdgcn_mfma_f32_16x16x32_bf16(a0, b0, acc, 0, 0, 0);
  acc = __builtin_amdgcn_mfma_f32_16x16x32_bf16(a1, b1, acc, 0, 0, 0);
  acc = __builtin_amdgcn_mfma_f32_16x16x32_bf16(x2, b2, acc, 0, 0, 0);
  acc = __builtin_amdgcn_mfma_f32_16x16x32_bf16(x3, b3, acc, 0, 0, 0);
  __syncthreads();  // all A reads done before C overwrites aw

  // ---- relu -> C staging (C layout: col=lane&15, row=quad*4+reg) ----
#pragma unroll
  for (int r = 0; r < 4; ++r)
    aw[(quad * 4 + r) * AST + c * 16 + m16] = f2bf(fmaxf(acc[r], 0.f));
  __syncthreads();

  if (!doProj) {
    // coalesced tile store: thread covers 8 B; row = tid>>4, chunk = tid&15
    int row = threadIdx.x >> 4, ch = threadIdx.x & 15;
    uint2 v = *(const uint2*)(aw + row * AST + ch * 4);
    *(uint2*)(xout + (long)(nb + row) * HD + ch * 4) = v;
  } else if (w == 0) {
    // projection: relu_tile [16x64] @ Wo [64x16] + bo
    short8 pa0 = *(const short8*)(aw + m16 * AST + quad * 8);
    short8 pa1 = *(const short8*)(aw + m16 * AST + 32 + quad * 8);
    const short8* pb = (const short8*)pfrag;
    short8 pb0 = pb[lane];
    short8 pb1 = pb[64 + lane];
    float bv = sbo[m16];
    f32x4 pacc = (f32x4){bv, bv, bv, bv};
    pacc = __builtin_amdgcn_mfma_f32_16x16x32_bf16(pa0, pb0, pacc, 0, 0, 0);
    pacc = __builtin_amdgcn_mfma_f32_16x16x32_bf16(pa1, pb1, pacc, 0, 0, 0);
    if (f32m) {
      float* o = (float*)outp;
#pragma unroll
      for (int r = 0; r < 4; ++r)
        o[(long)(nb + quad * 4 + r) * OD + m16] = pacc[r];
    } else {
      u16* o = (u16*)outp;
#pragma unroll
      for (int r = 0; r < 4; ++r)
        o[(long)(nb + quad * 4 + r) * OD + m16] = f2bf(pacc[r]);
    }
  }
}

extern "C" void kernel_launch(void* const* d_in, const int* in_sizes, int n_in,
                              void* d_out, int out_size, void* d_ws, size_t ws_size,
                              hipStream_t stream) {
  const void* x = d_in[0];
  const void* eidx = d_in[1];
  const void* Wl = d_in[2];
  const void* bl = d_in[3];
  const void* Wr = d_in[4];
  const void* Wo = d_in[5];
  const void* bo = d_in[6];

  char* w = (char*)d_ws;
  size_t off = 0;
  int* flags = (int*)(w + off);     off += 256;   // [4]=spillcnt
  int* deg = (int*)(w + off);       off += (size_t)NN * 4 + 192;
  size_t memset_bytes = off;                      // one memset: flags+deg
  u16* csr = (u16*)(w + off);       off += (size_t)NN * CAP * 2;   // 6.4 MB
  u32* spill = (u32*)(w + off);     off += (size_t)NE * 4;         // 3.2 MB
  u16* wfrag = (u16*)(w + off);     off += 3 * 16 * 64 * 8 * 2;
  u16* pfrag = (u16*)(w + off);     off += 2 * 64 * 8 * 2;
  float* blf = (float*)(w + off);   off += 3 * HD * 4;
  float* bof = (float*)(w + off);   off += 256;
  u16* xA = (u16*)(w + off);        off += (size_t)NN * HD * 2;
  u16* xB = (u16*)(w + off);        off += (size_t)NN * HD * 2;

  hipMemsetAsync(flags, 0, memset_bytes, stream);

  k_pre<<<SCATB + 3125, 256, 0, stream>>>(x, eidx, Wl, bl, Wr, Wo, bo,
                                          deg, csr, spill, xA, wfrag, pfrag,
                                          blf, bof, flags);

  const u32* xo32 = (const u32*)x;
  // L0: (x|xA) -> xB ; L1: xB -> xA ; L2: xA -> d_out (fused projection)
  k_fused<<<TILES, 256, 0, stream>>>((const u16*)x, xA, xo32, xB, deg, csr, spill,
                                     wfrag, pfrag, blf, bof, (void*)0, 0, 0, flags);
  k_fused<<<TILES, 256, 0, stream>>>(xB, xB, xo32, xA, deg, csr, spill,
                                     wfrag, pfrag, blf, bof, (void*)0, 1, 0, flags);
  k_fused<<<TILES, 256, 0, stream>>>(xA, xA, xo32, (u16*)0, deg, csr, spill,
                                     wfrag, pfrag, blf, bof, d_out, 2, 1, flags);
}